// Round 8
// baseline (261.284 us; speedup 1.0000x reference)
//
#include <hip/hip_runtime.h>

typedef short  short8  __attribute__((ext_vector_type(8)));
typedef short  short4v __attribute__((ext_vector_type(4)));
typedef float  float4v __attribute__((ext_vector_type(4)));
typedef int    int4v   __attribute__((ext_vector_type(4)));
typedef int    int2v   __attribute__((ext_vector_type(2)));

#define LOG2E 1.4426950408889634f

static __device__ __forceinline__ short f2bf(float f) {
  unsigned u = __builtin_bit_cast(unsigned, f);
  u = (u + 0x7fffu + ((u >> 16) & 1u)) >> 16;   // RNE
  return (short)u;
}
static __device__ __forceinline__ float bf2f(short s) {
  return __builtin_bit_cast(float, ((unsigned)(unsigned short)s) << 16);
}

// ---------------------------------------------------------------------------
// Kernel 0: pack adj (268 MB int32 0/1) -> bitmask (8 MB). Pays the adj HBM
// roofline once, perfectly coalesced (128B/thread), NT loads (adj never
// re-read; don't evict L2/L3). bits[w] bit b = adj[w*32 + b].
// ---------------------------------------------------------------------------
__global__ __launch_bounds__(256) void k_pack(
    const int* __restrict__ adj, unsigned* __restrict__ bits) {
  const int w0 = blockIdx.x * 256 + threadIdx.x;
  #pragma unroll
  for (int it = 0; it < 4; ++it) {
    const int w = w0 + it * 524288;
    const int4v* p = (const int4v*)(adj + (size_t)w * 32);
    unsigned m = 0;
    #pragma unroll
    for (int c = 0; c < 8; ++c) {
      int4v v = __builtin_nontemporal_load(p + c);
      m |= (v[0] != 0 ? 1u : 0u) << (c * 4);
      m |= (v[1] != 0 ? 1u : 0u) << (c * 4 + 1);
      m |= (v[2] != 0 ? 1u : 0u) << (c * 4 + 2);
      m |= (v[3] != 0 ? 1u : 0u) << (c * 4 + 3);
    }
    bits[w] = m;
  }
}

// ---------------------------------------------------------------------------
// Kernel 1: h = x @ w.T  (8192x256, K=256), hi/lo bf16-split MFMA for ~f32
// accuracy. Writes hT bf16 [256][8192] (ws) and hT f32 [256][8192] (d_out,
// transient — consumed by k_scores1; d_out fully rewritten by k_out).
// ---------------------------------------------------------------------------
__global__ __launch_bounds__(256) void k_hgemm(
    const float* __restrict__ x, const float* __restrict__ w,
    short* __restrict__ hT, float* __restrict__ hTf) {
  const int I0   = blockIdx.x * 64;
  const int lane = threadIdx.x & 63;
  const int wn   = threadIdx.x >> 6;       // 4 waves split N (cols)
  const int lrow = lane & 15;
  const int lk8  = (lane >> 4) << 3;

  float4v zero4 = {0.f, 0.f, 0.f, 0.f};
  float4v acc[4][4];
  #pragma unroll
  for (int mi = 0; mi < 4; ++mi)
    #pragma unroll
    for (int ni = 0; ni < 4; ++ni) acc[mi][ni] = zero4;

  for (int k0 = 0; k0 < 256; k0 += 32) {
    short8 ah[4], al[4], bh[4], bl[4];
    #pragma unroll
    for (int mi = 0; mi < 4; ++mi) {
      const float* xp = x + (size_t)(I0 + mi * 16 + lrow) * 256 + k0 + lk8;
      float4v va = *(const float4v*)xp;
      float4v vb = *(const float4v*)(xp + 4);
      #pragma unroll
      for (int e = 0; e < 4; ++e) {
        short h = f2bf(va[e]); ah[mi][e] = h;     al[mi][e]     = f2bf(va[e] - bf2f(h));
        h = f2bf(vb[e]);       ah[mi][4 + e] = h; al[mi][4 + e] = f2bf(vb[e] - bf2f(h));
      }
    }
    #pragma unroll
    for (int ni = 0; ni < 4; ++ni) {
      const float* wp = w + (size_t)(wn * 64 + ni * 16 + lrow) * 256 + k0 + lk8;
      float4v va = *(const float4v*)wp;
      float4v vb = *(const float4v*)(wp + 4);
      #pragma unroll
      for (int e = 0; e < 4; ++e) {
        short h = f2bf(va[e]); bh[ni][e] = h;     bl[ni][e]     = f2bf(va[e] - bf2f(h));
        h = f2bf(vb[e]);       bh[ni][4 + e] = h; bl[ni][4 + e] = f2bf(vb[e] - bf2f(h));
      }
    }
    #pragma unroll
    for (int mi = 0; mi < 4; ++mi)
      #pragma unroll
      for (int ni = 0; ni < 4; ++ni) {
        acc[mi][ni] = __builtin_amdgcn_mfma_f32_16x16x32_bf16(al[mi], bh[ni], acc[mi][ni], 0, 0, 0);
        acc[mi][ni] = __builtin_amdgcn_mfma_f32_16x16x32_bf16(ah[mi], bl[ni], acc[mi][ni], 0, 0, 0);
        acc[mi][ni] = __builtin_amdgcn_mfma_f32_16x16x32_bf16(ah[mi], bh[ni], acc[mi][ni], 0, 0, 0);
      }
  }
  const int r0 = (lane >> 4) << 2;   // C/D: col=lane&15, row=(lane>>4)*4+reg
  #pragma unroll
  for (int mi = 0; mi < 4; ++mi)
    #pragma unroll
    for (int ni = 0; ni < 4; ++ni) {
      const int c   = wn * 64 + ni * 16 + lrow;
      const int row = I0 + mi * 16 + r0;
      float4v v = acc[mi][ni];
      short4v sv;
      #pragma unroll
      for (int r = 0; r < 4; ++r) sv[r] = f2bf(v[r]);
      *(short4v*)(hT + (size_t)c * 8192 + row) = sv;
      *(float4v*)(hTf + (size_t)c * 8192 + row) = v;
    }
}

// ---------------------------------------------------------------------------
// Kernel 2: s1 = h@a1, s2 = h@a2 partials (split-K = 2)
// ---------------------------------------------------------------------------
__global__ __launch_bounds__(256) void k_scores1(
    const float* __restrict__ hTf, const float* __restrict__ a,
    float* __restrict__ t1p, float* __restrict__ t2p) {
  const int i = blockIdx.x * 256 + threadIdx.x;
  const int q = blockIdx.y;
  float s1 = 0.f, s2 = 0.f;
  #pragma unroll 8
  for (int kf = q * 128; kf < q * 128 + 128; ++kf) {
    float hv = hTf[(size_t)kf * 8192 + i];
    s1 = fmaf(hv, a[kf], s1);
    s2 = fmaf(hv, a[256 + kf], s2);
  }
  t1p[q * 8192 + i] = s1;
  t2p[q * 8192 + i] = s2;
}

// ---------------------------------------------------------------------------
// Kernel 3: reduce partials, emit exp2 tables:
//   e1f1[i] = {exp2(t1c), exp2(0.2 t1c)},  ef2[j] = {exp2(t2c), exp2(0.2 t2c)}
// so W = bit ? max(e1*e2, f1*f2) : 1  (exp2 of leaky-relu separable via
// monotonicity — no per-element transcendental in k_gat).
// ---------------------------------------------------------------------------
__global__ __launch_bounds__(256) void k_scores2(
    const float* __restrict__ t1p, const float* __restrict__ t2p,
    float2* __restrict__ e1f1, float2* __restrict__ ef2) {
  const int i = blockIdx.x * 256 + threadIdx.x;
  const float t1 = LOG2E * (t1p[i] + t1p[8192 + i]);
  const float t2 = LOG2E * (t2p[i] + t2p[8192 + i]);
  e1f1[i] = make_float2(exp2f(t1), exp2f(0.2f * t1));
  ef2[i]  = make_float2(exp2f(t2), exp2f(0.2f * t2));
}

// ---------------------------------------------------------------------------
// Kernel 4: fused GAT GEMM with NO HBM in the inner loop (r6/r7 showed a
// fixed ~10K cy/step cost from lockstep HBM bursts at barriers). Per-step
// global traffic: bitmask 2KB (L2-hot) + hT tile 64KB (L2-resident, 64x
// reuse); ef tables live in LDS (loaded once). BM=128 BN=256 BK=128,
// split-K=4: grid (64,4) = 256 blocks = 1/CU, 512 thr = 8 waves (2m x 4n),
// 16 steps. 256B-row &15 XOR swizzle -> conflict-free ds_read_b128 frags.
// Two barriers/step, single-buffered 116KB LDS; next-step loads issued
// after tiles-ready barrier (L2 latency covered by frag+MFMA phase).
// ---------------------------------------------------------------------------
__global__ __launch_bounds__(512) void k_gat(
    const unsigned* __restrict__ bits, const short* __restrict__ hT,
    const float2* __restrict__ e1f1, const float2* __restrict__ ef2,
    float* __restrict__ Np, float* __restrict__ Zp) {
  __shared__ __align__(16) char Wt[32768];     // [128][128] bf16, swz16
  __shared__ __align__(16) char Ht[65536];     // [256][128] bf16, swz16
  __shared__ __align__(16) float e2l[2304];    // 2048 f32, 16B pad per 32
  __shared__ __align__(16) float f2l[2304];
  __shared__ float zl[512];

  const int tid = threadIdx.x, lane = tid & 63, wave = tid >> 6;
  const int wm = wave >> 2, wn = wave & 3;
  const int lrow = lane & 15, lk16 = (lane >> 4) << 4;
  const int I0 = blockIdx.x * 128;
  const int j0 = blockIdx.y * 2048;

  // --- prologue: ef tables -> LDS (once per block)
  {
    const float4v* src = (const float4v*)(ef2 + j0 + tid * 4);
    float4v v0 = src[0], v1 = src[1];
    float4v e4, f4;
    e4[0] = v0[0]; f4[0] = v0[1]; e4[1] = v0[2]; f4[1] = v0[3];
    e4[2] = v1[0]; f4[2] = v1[1]; e4[3] = v1[2]; f4[3] = v1[3];
    const int pb = tid * 16 + (tid >> 3) * 16;
    *(float4v*)((char*)e2l + pb) = e4;
    *(float4v*)((char*)f2l + pb) = f4;
  }

  // --- W-compute mapping: thread -> (row rt, 32-j chunk jc)
  const int rt = tid >> 2;
  const int jc = (tid & 3) << 5;
  float e1v, f1v;
  { float2 v = e1f1[I0 + rt]; e1v = v.x; f1v = v.y; }
  const unsigned* mp = bits + (size_t)(I0 + rt) * 256 + (j0 >> 5) + (tid & 3);

  // --- H staging: thread -> row hf (+128 2nd pass), 4 x 16B at 64B stride
  //     (keeps every global load inst lane-contiguous: 16 segs of 64B)
  const int hf = tid >> 2;
  const int hco = (tid & 3) << 4;              // byte offset within 256B row
  const short* hgp0 = hT + (size_t)hf * 8192 + j0;
  const short* hgp1 = hgp0 + (size_t)128 * 8192;

  // --- LDS offsets
  const int wswz = (rt & 15) << 4;
  char* wwr = Wt + rt * 256;
  const int hswz = (hf & 15) << 4;             // (hf+128)&15 == hf&15
  char* hwr0 = Ht + hf * 256;
  char* hwr1 = Ht + (hf + 128) * 256;
  const char* ard = Wt + (wm * 64 + lrow) * 256;
  const char* brd = Ht + (wn * 64 + lrow) * 256;
  const int rsw = lrow << 4;                   // frag-read swizzle

  float4v zero4 = {0.f, 0.f, 0.f, 0.f};
  float4v acc[4][4];
  #pragma unroll
  for (int mi = 0; mi < 4; ++mi)
    #pragma unroll
    for (int ni = 0; ni < 4; ++ni) acc[mi][ni] = zero4;
  float zacc = 0.f;

  __syncthreads();                             // ef tables visible

  // --- step-0 loads
  unsigned m = mp[0];
  short8 gh0[4], gh1[4];
  #pragma unroll
  for (int i = 0; i < 4; ++i) {
    gh0[i] = *(const short8*)((const char*)hgp0 + hco + i * 64);
    gh1[i] = *(const short8*)((const char*)hgp1 + hco + i * 64);
  }

  for (int s = 0; s < 16; ++s) {
    // W-compute: 32 values from mask bits + LDS ef tables
    int4v pwa[4];
    #pragma unroll
    for (int q = 0; q < 8; ++q) {
      const int jj = s * 128 + jc + q * 4;
      const int pb = jj * 4 + ((jj >> 5) << 4);
      const float4v e2q = *(const float4v*)((const char*)e2l + pb);
      const float4v f2q = *(const float4v*)((const char*)f2l + pb);
      float w0 = ((m >> (q * 4 + 0)) & 1) ? fmaxf(e1v * e2q[0], f1v * f2q[0]) : 1.0f;
      float w1 = ((m >> (q * 4 + 1)) & 1) ? fmaxf(e1v * e2q[1], f1v * f2q[1]) : 1.0f;
      float w2 = ((m >> (q * 4 + 2)) & 1) ? fmaxf(e1v * e2q[2], f1v * f2q[2]) : 1.0f;
      float w3 = ((m >> (q * 4 + 3)) & 1) ? fmaxf(e1v * e2q[3], f1v * f2q[3]) : 1.0f;
      zacc += (w0 + w1) + (w2 + w3);
      asm("v_cvt_pk_bf16_f32 %0, %1, %2" : "=v"(pwa[q >> 1][(q & 1) * 2])     : "v"(w0), "v"(w1));
      asm("v_cvt_pk_bf16_f32 %0, %1, %2" : "=v"(pwa[q >> 1][(q & 1) * 2 + 1]) : "v"(w2), "v"(w3));
    }

    __syncthreads();                 // barrier-1: frag reads of s-1 complete
    #pragma unroll
    for (int i = 0; i < 4; ++i)
      *(int4v*)(wwr + ((jc * 2 + i * 16) ^ wswz)) = pwa[i];
    #pragma unroll
    for (int i = 0; i < 4; ++i) {
      *(short8*)(hwr0 + ((hco + i * 64) ^ hswz)) = gh0[i];
      *(short8*)(hwr1 + ((hco + i * 64) ^ hswz)) = gh1[i];
    }
    __syncthreads();                 // barrier-2: tiles ready

    // issue step-s+1 loads (L2-hot; covered by frag-read + MFMA phase)
    if (s < 15) {
      m = mp[(s + 1) * 4];
      const int so = (s + 1) * 256;  // byte offset (128 j * 2B)
      #pragma unroll
      for (int i = 0; i < 4; ++i) {
        gh0[i] = *(const short8*)((const char*)hgp0 + so + hco + i * 64);
        gh1[i] = *(const short8*)((const char*)hgp1 + so + hco + i * 64);
      }
    }

    // fragment reads (conflict-free) + 64 MFMA/wave
    #pragma unroll
    for (int kk = 0; kk < 4; ++kk) {
      const int ko = (kk * 64 + lk16) ^ rsw;
      short8 af[4], bf[4];
      #pragma unroll
      for (int mi = 0; mi < 4; ++mi) af[mi] = *(const short8*)(ard + mi * 4096 + ko);
      #pragma unroll
      for (int ni = 0; ni < 4; ++ni) bf[ni] = *(const short8*)(brd + ni * 4096 + ko);
      #pragma unroll
      for (int mi = 0; mi < 4; ++mi)
        #pragma unroll
        for (int ni = 0; ni < 4; ++ni)
          acc[mi][ni] = __builtin_amdgcn_mfma_f32_16x16x32_bf16(af[mi], bf[ni], acc[mi][ni], 0, 0, 0);
    }
  }

  // Z reduce: zl[tid] = thread partial for row rt (4 threads/row)
  zl[tid] = zacc;
  __syncthreads();
  if (tid < 128) {
    float z = zl[tid * 4] + zl[tid * 4 + 1] + zl[tid * 4 + 2] + zl[tid * 4 + 3];
    Zp[(size_t)blockIdx.y * 8192 + I0 + tid] = z;
  }

  // N partial store (direct, no atomics)
  float* Npb = Np + (size_t)blockIdx.y * 2097152;
  const int r0 = (lane >> 4) << 2;
  #pragma unroll
  for (int mi = 0; mi < 4; ++mi) {
    const int rowb = I0 + wm * 64 + mi * 16 + r0;
    #pragma unroll
    for (int ni = 0; ni < 4; ++ni) {
      const int col = wn * 64 + ni * 16 + lrow;
      #pragma unroll
      for (int r = 0; r < 4; ++r)
        Npb[(size_t)(rowb + r) * 256 + col] = acc[mi][ni][r];
    }
  }
}

// ---------------------------------------------------------------------------
// Kernel 5: out = elu( (sum_y Np) / (sum_y Zp) )   (4 split-K slabs)
// ---------------------------------------------------------------------------
__global__ __launch_bounds__(256) void k_out(
    const float* __restrict__ Np, const float* __restrict__ Zp,
    float* __restrict__ out) {
  const int idx = blockIdx.x * 256 + threadIdx.x;   // float4 index
  const int i = idx >> 6;                           // row (256 feat = 64 f4)
  float z = 0.f;
  #pragma unroll
  for (int y = 0; y < 4; ++y) z += Zp[y * 8192 + i];
  float4v n = {0.f, 0.f, 0.f, 0.f};
  #pragma unroll
  for (int y = 0; y < 4; ++y) {
    float4v v = ((const float4v*)Np)[(size_t)y * 524288 + idx];
    #pragma unroll
    for (int e = 0; e < 4; ++e) n[e] += v[e];
  }
  const float rz = 1.0f / z;
  float4v o;
  #pragma unroll
  for (int e = 0; e < 4; ++e) {
    float v = n[e] * rz;
    o[e] = (v > 0.f) ? v : expm1f(v);
  }
  ((float4v*)out)[idx] = o;
}

// ---------------------------------------------------------------------------
extern "C" void kernel_launch(void* const* d_in, const int* in_sizes, int n_in,
                              void* d_out, int out_size, void* d_ws, size_t ws_size,
                              hipStream_t stream) {
  const int*   adj = (const int*)d_in[0];
  const float* x   = (const float*)d_in[1];
  const float* w   = (const float*)d_in[2];
  const float* a   = (const float*)d_in[3];
  float* out = (float*)d_out;

  // ws layout (~48 MiB of the ~1 GiB ws). hTf (8 MiB f32) lives in d_out
  // transiently; k_out rewrites d_out entirely each call.
  char* ws = (char*)d_ws;
  short*    hT   = (short*)(ws + 0);            //  4 MiB bf16 h^T [256][8192]
  unsigned* bits = (unsigned*)(ws + 4194304);   //  8 MiB adj bitmask
  float*    t1p  = (float*)(ws + 12582912);     // 64 KiB
  float*    t2p  = (float*)(ws + 12648448);     // 64 KiB
  float2*   e1f1 = (float2*)(ws + 12713984);    // 64 KiB
  float2*   ef2  = (float2*)(ws + 12779520);    // 64 KiB
  float*    Zp   = (float*)(ws + 12845056);     // 128 KiB (4 x 8192)
  float*    Np   = (float*)(ws + 16777216);     // 32 MiB (4 x 8192 x 256)
  float*    hTf  = (float*)d_out;               //  8 MiB f32 h^T (transient)

  k_pack   <<<2048, 256, 0, stream>>>(adj, bits);
  k_hgemm  <<<128, 256, 0, stream>>>(x, w, hT, hTf);
  k_scores1<<<dim3(32, 2), 256, 0, stream>>>(hTf, a, t1p, t2p);
  k_scores2<<<32, 256, 0, stream>>>(t1p, t2p, e1f1, ef2);
  k_gat    <<<dim3(64, 4), 512, 0, stream>>>(bits, hT, e1f1, ef2, Np, Zp);
  k_out    <<<2048, 256, 0, stream>>>(Np, Zp, out);
}

// Round 9
// 174.349 us; speedup vs baseline: 1.4986x; 1.4986x over previous
//
#include <hip/hip_runtime.h>

typedef short  short8  __attribute__((ext_vector_type(8)));
typedef short  short4v __attribute__((ext_vector_type(4)));
typedef float  float4v __attribute__((ext_vector_type(4)));
typedef int    int4v   __attribute__((ext_vector_type(4)));
typedef int    int2v   __attribute__((ext_vector_type(2)));

#define LOG2E 1.4426950408889634f

static __device__ __forceinline__ short f2bf(float f) {
  unsigned u = __builtin_bit_cast(unsigned, f);
  u = (u + 0x7fffu + ((u >> 16) & 1u)) >> 16;   // RNE
  return (short)u;
}
static __device__ __forceinline__ float bf2f(short s) {
  return __builtin_bit_cast(float, ((unsigned)(unsigned short)s) << 16);
}

// ---------------------------------------------------------------------------
// Kernel 1: h = x @ w.T  (8192x256, K=256), hi/lo bf16-split MFMA for ~f32
// accuracy. Writes hT bf16 [256][8192] (ws) and hT f32 [256][8192] (d_out,
// transient — consumed by k_scores1; d_out fully rewritten by k_out).
// ---------------------------------------------------------------------------
__global__ __launch_bounds__(256) void k_hgemm(
    const float* __restrict__ x, const float* __restrict__ w,
    short* __restrict__ hT, float* __restrict__ hTf) {
  const int I0   = blockIdx.x * 64;
  const int lane = threadIdx.x & 63;
  const int wn   = threadIdx.x >> 6;       // 4 waves split N (cols)
  const int lrow = lane & 15;
  const int lk8  = (lane >> 4) << 3;

  float4v zero4 = {0.f, 0.f, 0.f, 0.f};
  float4v acc[4][4];
  #pragma unroll
  for (int mi = 0; mi < 4; ++mi)
    #pragma unroll
    for (int ni = 0; ni < 4; ++ni) acc[mi][ni] = zero4;

  for (int k0 = 0; k0 < 256; k0 += 32) {
    short8 ah[4], al[4], bh[4], bl[4];
    #pragma unroll
    for (int mi = 0; mi < 4; ++mi) {
      const float* xp = x + (size_t)(I0 + mi * 16 + lrow) * 256 + k0 + lk8;
      float4v va = *(const float4v*)xp;
      float4v vb = *(const float4v*)(xp + 4);
      #pragma unroll
      for (int e = 0; e < 4; ++e) {
        short h = f2bf(va[e]); ah[mi][e] = h;     al[mi][e]     = f2bf(va[e] - bf2f(h));
        h = f2bf(vb[e]);       ah[mi][4 + e] = h; al[mi][4 + e] = f2bf(vb[e] - bf2f(h));
      }
    }
    #pragma unroll
    for (int ni = 0; ni < 4; ++ni) {
      const float* wp = w + (size_t)(wn * 64 + ni * 16 + lrow) * 256 + k0 + lk8;
      float4v va = *(const float4v*)wp;
      float4v vb = *(const float4v*)(wp + 4);
      #pragma unroll
      for (int e = 0; e < 4; ++e) {
        short h = f2bf(va[e]); bh[ni][e] = h;     bl[ni][e]     = f2bf(va[e] - bf2f(h));
        h = f2bf(vb[e]);       bh[ni][4 + e] = h; bl[ni][4 + e] = f2bf(vb[e] - bf2f(h));
      }
    }
    #pragma unroll
    for (int mi = 0; mi < 4; ++mi)
      #pragma unroll
      for (int ni = 0; ni < 4; ++ni) {
        acc[mi][ni] = __builtin_amdgcn_mfma_f32_16x16x32_bf16(al[mi], bh[ni], acc[mi][ni], 0, 0, 0);
        acc[mi][ni] = __builtin_amdgcn_mfma_f32_16x16x32_bf16(ah[mi], bl[ni], acc[mi][ni], 0, 0, 0);
        acc[mi][ni] = __builtin_amdgcn_mfma_f32_16x16x32_bf16(ah[mi], bh[ni], acc[mi][ni], 0, 0, 0);
      }
  }
  const int r0 = (lane >> 4) << 2;   // C/D: col=lane&15, row=(lane>>4)*4+reg
  #pragma unroll
  for (int mi = 0; mi < 4; ++mi)
    #pragma unroll
    for (int ni = 0; ni < 4; ++ni) {
      const int c   = wn * 64 + ni * 16 + lrow;
      const int row = I0 + mi * 16 + r0;
      float4v v = acc[mi][ni];
      short4v sv;
      #pragma unroll
      for (int r = 0; r < 4; ++r) sv[r] = f2bf(v[r]);
      *(short4v*)(hT + (size_t)c * 8192 + row) = sv;
      *(float4v*)(hTf + (size_t)c * 8192 + row) = v;
    }
}

// ---------------------------------------------------------------------------
// Kernel 2: s1 = h@a1, s2 = h@a2 partials (split-K = 2)
// ---------------------------------------------------------------------------
__global__ __launch_bounds__(256) void k_scores1(
    const float* __restrict__ hTf, const float* __restrict__ a,
    float* __restrict__ t1p, float* __restrict__ t2p) {
  const int i = blockIdx.x * 256 + threadIdx.x;
  const int q = blockIdx.y;
  float s1 = 0.f, s2 = 0.f;
  #pragma unroll 8
  for (int kf = q * 128; kf < q * 128 + 128; ++kf) {
    float hv = hTf[(size_t)kf * 8192 + i];
    s1 = fmaf(hv, a[kf], s1);
    s2 = fmaf(hv, a[256 + kf], s2);
  }
  t1p[q * 8192 + i] = s1;
  t2p[q * 8192 + i] = s2;
}

// ---------------------------------------------------------------------------
// Kernel 3: reduce partials, emit exp2 tables:
//   e1f1[i] = {exp2(t1c), exp2(0.2 t1c)},  ef2[j] = {exp2(t2c), exp2(0.2 t2c)}
// so W = adj ? max(e1*e2, f1*f2) : 1  (exp2 of leaky-relu separable via
// monotonicity — no per-element transcendental in k_gat).
// ---------------------------------------------------------------------------
__global__ __launch_bounds__(256) void k_scores2(
    const float* __restrict__ t1p, const float* __restrict__ t2p,
    float2* __restrict__ e1f1, float2* __restrict__ ef2) {
  const int i = blockIdx.x * 256 + threadIdx.x;
  const float t1 = LOG2E * (t1p[i] + t1p[8192 + i]);
  const float t2 = LOG2E * (t2p[i] + t2p[8192 + i]);
  e1f1[i] = make_float2(exp2f(t1), exp2f(0.2f * t1));
  ef2[i]  = make_float2(exp2f(t2), exp2f(0.2f * t2));
}

// ---------------------------------------------------------------------------
// Kernel 4: fused GAT GEMM, r6 structure + the bank-conflict fix.
// KEY FIX: LDS rows padded to 144B (128B data + 16B). 128B/256B rows are
// bank-aligned (every row starts at bank 0), and the 16x16x32 frag read
// (lane l: row l&15, chunk l>>4) then aliases 8 lanes/bank-group = 8-way
// conflict on EVERY ds_read_b128 — present in r6/r7/r8, the dominant
// serialized phase. 144B stride rotates rows by 4 banks: bank group =
// 4*((l&15)+(l>>4))%32 -> exactly 8 lanes per 4-bank group = zero conflict.
// No XOR swizzle anywhere. BM=128 BN=256 BK=64, split-K=8: grid (64,8) =
// 512 blocks = 2/CU (LDS 55.3KB, VGPR capped 128) so the co-resident
// block's compute covers this block's barrier/memory phases. Direct adj
// reads (coalesced, NT); ef tables via L1; loads for s+1 issued after the
// tiles-ready barrier. Z = per-thread scalar partials -> LDS reduce.
// ---------------------------------------------------------------------------
__global__ __launch_bounds__(512, 4) void k_gat(
    const int* __restrict__ adj, const short* __restrict__ hT,
    const float2* __restrict__ e1f1, const float2* __restrict__ ef2,
    float* __restrict__ Np, float* __restrict__ Zp) {
  __shared__ __align__(16) char Wt[18432];     // 128 rows x 144B (64j bf16 + pad)
  __shared__ __align__(16) char Ht[36864];     // 256 rows x 144B
  __shared__ float zl[2048];                   // 128 rows x 16 thread-partials

  const int tid = threadIdx.x, lane = tid & 63, wave = tid >> 6;
  const int wm = wave >> 2, wn = wave & 3;
  const int lrow = lane & 15, lk16 = (lane >> 4) << 4;
  const int I0 = blockIdx.x * 128;
  const int j0 = blockIdx.y * 1024;

  // --- W staging map: thread -> rows ar+32p (p=0..3), j-chunk ajc (4 j)
  const int ar = tid >> 4, ajc = (tid & 15) * 4;
  const int*    agp = adj + (size_t)(I0 + ar) * 8192 + j0 + ajc;
  const float2* efp = ef2 + j0 + ajc;
  float e1p[4], f1p[4];
  #pragma unroll
  for (int p = 0; p < 4; ++p) {
    float2 v = e1f1[I0 + p * 32 + ar];
    e1p[p] = v.x; f1p[p] = v.y;
  }
  char* wwr = Wt + ar * 144 + ajc * 2;         // +p*32*144

  // --- H staging map: thread -> rows hf+64p, 16B chunk
  const int hf = tid >> 3, hjc = (tid & 7) * 8;
  const short* hgp = hT + (size_t)hf * 8192 + j0 + hjc;
  char* hwr = Ht + hf * 144 + hjc * 2;         // +p*64*144

  // --- frag-read bases (144B stride -> zero-conflict, no swizzle)
  const char* ard = Wt + (wm * 64 + lrow) * 144 + lk16;
  const char* brd = Ht + (wn * 64 + lrow) * 144 + lk16;

  float4v zero4 = {0.f, 0.f, 0.f, 0.f};
  float4v acc[4][4];
  #pragma unroll
  for (int mi = 0; mi < 4; ++mi)
    #pragma unroll
    for (int ni = 0; ni < 4; ++ni) acc[mi][ni] = zero4;
  float zacc[4] = {0.f, 0.f, 0.f, 0.f};

  // --- step-0 loads
  int4v  ga[4];
  short8 gh[4];
  float4v ge0, ge1;
  #pragma unroll
  for (int p = 0; p < 4; ++p) {
    ga[p] = __builtin_nontemporal_load((const int4v*)(agp + (size_t)p * 262144));
    gh[p] = *(const short8*)(hgp + (size_t)p * 524288);
  }
  ge0 = *(const float4v*)(efp);
  ge1 = *(const float4v*)(efp + 2);

  for (int s = 0; s < 16; ++s) {
    // W-compute (regs): 16 values/thread, Z scalar partials
    int2v pw[4];
    #pragma unroll
    for (int p = 0; p < 4; ++p) {
      float w0 = ga[p][0] ? fmaxf(e1p[p] * ge0[0], f1p[p] * ge0[1]) : 1.0f;
      float w1 = ga[p][1] ? fmaxf(e1p[p] * ge0[2], f1p[p] * ge0[3]) : 1.0f;
      float w2 = ga[p][2] ? fmaxf(e1p[p] * ge1[0], f1p[p] * ge1[1]) : 1.0f;
      float w3 = ga[p][3] ? fmaxf(e1p[p] * ge1[2], f1p[p] * ge1[3]) : 1.0f;
      zacc[p] += (w0 + w1) + (w2 + w3);
      asm("v_cvt_pk_bf16_f32 %0, %1, %2" : "=v"(pw[p][0]) : "v"(w0), "v"(w1));
      asm("v_cvt_pk_bf16_f32 %0, %1, %2" : "=v"(pw[p][1]) : "v"(w2), "v"(w3));
    }

    __syncthreads();                 // barrier-1: step s-1 frag reads done
    #pragma unroll
    for (int p = 0; p < 4; ++p) {
      *(int2v*)(wwr + p * 4608) = pw[p];     // 32 rows * 144B
      *(short8*)(hwr + p * 9216) = gh[p];    // 64 rows * 144B
    }
    __syncthreads();                 // barrier-2: tiles ready

    // issue step-s+1 loads; latency hides under frag reads + MFMA (plus the
    // co-resident block's compute)
    if (s < 15) {
      const int so = (s + 1) * 64;
      #pragma unroll
      for (int p = 0; p < 4; ++p) {
        ga[p] = __builtin_nontemporal_load((const int4v*)(agp + (size_t)p * 262144 + so));
        gh[p] = *(const short8*)(hgp + (size_t)p * 524288 + so);
      }
      ge0 = *(const float4v*)(efp + so);
      ge1 = *(const float4v*)(efp + so + 2);
    }

    // frag reads (zero-conflict) + 32 MFMA/wave
    #pragma unroll
    for (int kk = 0; kk < 2; ++kk) {
      short8 af[4], bf[4];
      #pragma unroll
      for (int mi = 0; mi < 4; ++mi) af[mi] = *(const short8*)(ard + mi * 2304 + kk * 64);
      #pragma unroll
      for (int ni = 0; ni < 4; ++ni) bf[ni] = *(const short8*)(brd + ni * 2304 + kk * 64);
      #pragma unroll
      for (int mi = 0; mi < 4; ++mi)
        #pragma unroll
        for (int ni = 0; ni < 4; ++ni)
          acc[mi][ni] = __builtin_amdgcn_mfma_f32_16x16x32_bf16(af[mi], bf[ni], acc[mi][ni], 0, 0, 0);
    }
  }

  // Z reduce: zl[row][c] over 16 thread-partials per row
  __syncthreads();
  #pragma unroll
  for (int p = 0; p < 4; ++p) zl[(ar + p * 32) * 16 + (tid & 15)] = zacc[p];
  __syncthreads();
  if (tid < 128) {
    float z = 0.f;
    #pragma unroll
    for (int g = 0; g < 16; ++g) z += zl[tid * 16 + g];
    Zp[(size_t)blockIdx.y * 8192 + I0 + tid] = z;
  }

  // N partial store (direct, no atomics)
  float* Npb = Np + (size_t)blockIdx.y * 2097152;
  const int r0 = (lane >> 4) << 2;
  #pragma unroll
  for (int mi = 0; mi < 4; ++mi) {
    const int rowb = I0 + wm * 64 + mi * 16 + r0;
    #pragma unroll
    for (int ni = 0; ni < 4; ++ni) {
      const int col = wn * 64 + ni * 16 + lrow;
      #pragma unroll
      for (int r = 0; r < 4; ++r)
        Npb[(size_t)(rowb + r) * 256 + col] = acc[mi][ni][r];
    }
  }
}

// ---------------------------------------------------------------------------
// Kernel 5: out = elu( (sum_y Np) / (sum_y Zp) )   (8 split-K slabs)
// ---------------------------------------------------------------------------
__global__ __launch_bounds__(256) void k_out(
    const float* __restrict__ Np, const float* __restrict__ Zp,
    float* __restrict__ out) {
  const int idx = blockIdx.x * 256 + threadIdx.x;   // float4 index
  const int i = idx >> 6;                           // row (256 feat = 64 f4)
  float z = 0.f;
  #pragma unroll
  for (int y = 0; y < 8; ++y) z += Zp[y * 8192 + i];
  float4v n = {0.f, 0.f, 0.f, 0.f};
  #pragma unroll
  for (int y = 0; y < 8; ++y) {
    float4v v = ((const float4v*)Np)[(size_t)y * 524288 + idx];
    #pragma unroll
    for (int e = 0; e < 4; ++e) n[e] += v[e];
  }
  const float rz = 1.0f / z;
  float4v o;
  #pragma unroll
  for (int e = 0; e < 4; ++e) {
    float v = n[e] * rz;
    o[e] = (v > 0.f) ? v : expm1f(v);
  }
  ((float4v*)out)[idx] = o;
}

// ---------------------------------------------------------------------------
extern "C" void kernel_launch(void* const* d_in, const int* in_sizes, int n_in,
                              void* d_out, int out_size, void* d_ws, size_t ws_size,
                              hipStream_t stream) {
  const int*   adj = (const int*)d_in[0];
  const float* x   = (const float*)d_in[1];
  const float* w   = (const float*)d_in[2];
  const float* a   = (const float*)d_in[3];
  float* out = (float*)d_out;

  // ws layout (~80 MiB of ~1 GiB). hTf (8 MiB f32) lives in d_out
  // transiently; k_out rewrites d_out entirely each call.
  char* ws = (char*)d_ws;
  short*  hT   = (short*)(ws + 0);          //  4 MiB bf16 h^T [256][8192]
  float*  t1p  = (float*)(ws + 4194304);    // 64 KiB
  float*  t2p  = (float*)(ws + 4259840);    // 64 KiB
  float2* e1f1 = (float2*)(ws + 4325376);   // 64 KiB
  float2* ef2  = (float2*)(ws + 4390912);   // 64 KiB
  float*  Zp   = (float*)(ws + 4456448);    // 256 KiB (8 x 8192)
  float*  Np   = (float*)(ws + 16777216);   // 64 MiB (8 x 8192 x 256)
  float*  hTf  = (float*)d_out;             //  8 MiB f32 h^T (transient)

  k_hgemm  <<<128, 256, 0, stream>>>(x, w, hT, hTf);
  k_scores1<<<dim3(32, 2), 256, 0, stream>>>(hTf, a, t1p, t2p);
  k_scores2<<<32, 256, 0, stream>>>(t1p, t2p, e1f1, ef2);
  k_gat    <<<dim3(64, 8), 512, 0, stream>>>(adj, hT, e1f1, ef2, Np, Zp);
  k_out    <<<2048, 256, 0, stream>>>(Np, Zp, out);
}

// Round 10
// 165.965 us; speedup vs baseline: 1.5743x; 1.0505x over previous
//
#include <hip/hip_runtime.h>

typedef short  short8  __attribute__((ext_vector_type(8)));
typedef short  short4v __attribute__((ext_vector_type(4)));
typedef float  float4v __attribute__((ext_vector_type(4)));
typedef int    int4v   __attribute__((ext_vector_type(4)));
typedef int    int2v   __attribute__((ext_vector_type(2)));

#define LOG2E 1.4426950408889634f

static __device__ __forceinline__ short f2bf(float f) {
  unsigned u = __builtin_bit_cast(unsigned, f);
  u = (u + 0x7fffu + ((u >> 16) & 1u)) >> 16;   // RNE
  return (short)u;
}
static __device__ __forceinline__ float bf2f(short s) {
  return __builtin_bit_cast(float, ((unsigned)(unsigned short)s) << 16);
}

typedef __attribute__((address_space(3))) char  as3c;
typedef __attribute__((address_space(1))) char  as1c;
static __device__ __forceinline__ void dma16(const void* g, void* l) {
  __builtin_amdgcn_global_load_lds((const as1c*)g, (as3c*)l, 16, 0, 0);
}

// ---------------------------------------------------------------------------
// Kernel 1: h = x @ w.T  (8192x256, K=256), hi/lo bf16-split MFMA for ~f32
// accuracy. Writes hT bf16 [256][8192] (ws) and hT f32 [256][8192] (d_out,
// transient — consumed by k_scores1; d_out fully rewritten by k_out).
// ---------------------------------------------------------------------------
__global__ __launch_bounds__(256) void k_hgemm(
    const float* __restrict__ x, const float* __restrict__ w,
    short* __restrict__ hT, float* __restrict__ hTf) {
  const int I0   = blockIdx.x * 64;
  const int lane = threadIdx.x & 63;
  const int wn   = threadIdx.x >> 6;       // 4 waves split N (cols)
  const int lrow = lane & 15;
  const int lk8  = (lane >> 4) << 3;

  float4v zero4 = {0.f, 0.f, 0.f, 0.f};
  float4v acc[4][4];
  #pragma unroll
  for (int mi = 0; mi < 4; ++mi)
    #pragma unroll
    for (int ni = 0; ni < 4; ++ni) acc[mi][ni] = zero4;

  for (int k0 = 0; k0 < 256; k0 += 32) {
    short8 ah[4], al[4], bh[4], bl[4];
    #pragma unroll
    for (int mi = 0; mi < 4; ++mi) {
      const float* xp = x + (size_t)(I0 + mi * 16 + lrow) * 256 + k0 + lk8;
      float4v va = *(const float4v*)xp;
      float4v vb = *(const float4v*)(xp + 4);
      #pragma unroll
      for (int e = 0; e < 4; ++e) {
        short h = f2bf(va[e]); ah[mi][e] = h;     al[mi][e]     = f2bf(va[e] - bf2f(h));
        h = f2bf(vb[e]);       ah[mi][4 + e] = h; al[mi][4 + e] = f2bf(vb[e] - bf2f(h));
      }
    }
    #pragma unroll
    for (int ni = 0; ni < 4; ++ni) {
      const float* wp = w + (size_t)(wn * 64 + ni * 16 + lrow) * 256 + k0 + lk8;
      float4v va = *(const float4v*)wp;
      float4v vb = *(const float4v*)(wp + 4);
      #pragma unroll
      for (int e = 0; e < 4; ++e) {
        short h = f2bf(va[e]); bh[ni][e] = h;     bl[ni][e]     = f2bf(va[e] - bf2f(h));
        h = f2bf(vb[e]);       bh[ni][4 + e] = h; bl[ni][4 + e] = f2bf(vb[e] - bf2f(h));
      }
    }
    #pragma unroll
    for (int mi = 0; mi < 4; ++mi)
      #pragma unroll
      for (int ni = 0; ni < 4; ++ni) {
        acc[mi][ni] = __builtin_amdgcn_mfma_f32_16x16x32_bf16(al[mi], bh[ni], acc[mi][ni], 0, 0, 0);
        acc[mi][ni] = __builtin_amdgcn_mfma_f32_16x16x32_bf16(ah[mi], bl[ni], acc[mi][ni], 0, 0, 0);
        acc[mi][ni] = __builtin_amdgcn_mfma_f32_16x16x32_bf16(ah[mi], bh[ni], acc[mi][ni], 0, 0, 0);
      }
  }
  const int r0 = (lane >> 4) << 2;   // C/D: col=lane&15, row=(lane>>4)*4+reg
  #pragma unroll
  for (int mi = 0; mi < 4; ++mi)
    #pragma unroll
    for (int ni = 0; ni < 4; ++ni) {
      const int c   = wn * 64 + ni * 16 + lrow;
      const int row = I0 + mi * 16 + r0;
      float4v v = acc[mi][ni];
      short4v sv;
      #pragma unroll
      for (int r = 0; r < 4; ++r) sv[r] = f2bf(v[r]);
      *(short4v*)(hT + (size_t)c * 8192 + row) = sv;
      *(float4v*)(hTf + (size_t)c * 8192 + row) = v;
    }
}

// ---------------------------------------------------------------------------
// Kernel 2: s1 = h@a1, s2 = h@a2 partials (split-K = 2)
// ---------------------------------------------------------------------------
__global__ __launch_bounds__(256) void k_scores1(
    const float* __restrict__ hTf, const float* __restrict__ a,
    float* __restrict__ t1p, float* __restrict__ t2p) {
  const int i = blockIdx.x * 256 + threadIdx.x;
  const int q = blockIdx.y;
  float s1 = 0.f, s2 = 0.f;
  #pragma unroll 8
  for (int kf = q * 128; kf < q * 128 + 128; ++kf) {
    float hv = hTf[(size_t)kf * 8192 + i];
    s1 = fmaf(hv, a[kf], s1);
    s2 = fmaf(hv, a[256 + kf], s2);
  }
  t1p[q * 8192 + i] = s1;
  t2p[q * 8192 + i] = s2;
}

// ---------------------------------------------------------------------------
// Kernel 3: reduce partials, emit exp2 tables:
//   e1f1[i] = {exp2(t1c), exp2(0.2 t1c)},  ef2[j] = {exp2(t2c), exp2(0.2 t2c)}
// so W = adj ? max(e1*e2, f1*f2) : 1  (exp2 of leaky-relu separable via
// monotonicity — no per-element transcendental in k_gat).
// ---------------------------------------------------------------------------
__global__ __launch_bounds__(256) void k_scores2(
    const float* __restrict__ t1p, const float* __restrict__ t2p,
    float2* __restrict__ e1f1, float2* __restrict__ ef2) {
  const int i = blockIdx.x * 256 + threadIdx.x;
  const float t1 = LOG2E * (t1p[i] + t1p[8192 + i]);
  const float t2 = LOG2E * (t2p[i] + t2p[8192 + i]);
  e1f1[i] = make_float2(exp2f(t1), exp2f(0.2f * t1));
  ef2[i]  = make_float2(exp2f(t2), exp2f(0.2f * t2));
}

// ---------------------------------------------------------------------------
// Kernel 4: fused GAT GEMM — m97-template staging. H-tile staged via
// global_load_lds DMA (no VGPR round-trip, no H ds_writes — r9's stage
// chain was the serialized cost per m233's 2-phase anatomy). LDS linear
// for DMA; conflict-freedom via PRE-SWIZZLED per-lane global source
// (chunk g = c ^ (f&7)), reader applies the same XOR. W-tile (computed)
// uses a normal ds_write path with 136B-padded rows (bank-balanced).
// BM=128 BN=256 BK=64, split-K=8: grid (64,8) = 512 blocks = 2/CU
// (LDS 49KB, VGPR<=128). Schedule per step: MFMA(s) | barrier |
// DMA H(s+1) -> VALU W(s+1) covers DMA latency -> ds_write W | barrier
// (drains vmcnt: DMA complete) | issue adj(s+2) regs (covered by next
// MFMA phase). Z = per-thread scalars -> LDS reduce (aliased into Wt).
// ---------------------------------------------------------------------------
__global__ __launch_bounds__(512, 4) void k_gat(
    const int* __restrict__ adj, const short* __restrict__ hT,
    const float2* __restrict__ e1f1, const float2* __restrict__ ef2,
    float* __restrict__ Np, float* __restrict__ Zp) {
  __shared__ __align__(16) char Wt[17408];   // 128 rows x 136B (64j bf16 + 8B pad)
  __shared__ __align__(16) char Hb[32768];   // 256 rows x 128B, linear (DMA), src-swz

  const int tid = threadIdx.x, lane = tid & 63, wave = tid >> 6;
  const int wm = wave >> 2, wn = wave & 3;
  const int lrow = lane & 15, lk16 = (lane >> 4) << 4;
  const int I0 = blockIdx.x * 128;
  const int j0 = blockIdx.y * 1024;

  // --- W staging map: thread -> rows ar+32p (p=0..3), 4-j chunk ajc
  const int ar = tid >> 4, aj = tid & 15;
  const int* agp = adj + (size_t)(I0 + ar) * 8192 + j0 + aj * 4;
  const float* efp = (const float*)(ef2 + j0) + aj * 8;
  float e1p[4], f1p[4];
  #pragma unroll
  for (int p = 0; p < 4; ++p) {
    float2 v = e1f1[I0 + p * 32 + ar];
    e1p[p] = v.x; f1p[p] = v.y;
  }
  char* wwr = Wt + ar * 136 + aj * 8;          // + p*32*136 = p*4352

  // --- H DMA: wave handles rows wave*32..+31; per instr q: 8 rows.
  //     lane l -> row +(l>>3), global chunk (l&7)^(l>>3) (pre-swizzle).
  const int l8 = lane >> 3, l7 = lane & 7;
  const short* hdma = hT + (size_t)(wave * 32 + l8) * 8192 + j0 + (l7 ^ l8) * 8;
  char* hlds = Hb + wave * 4096;               // + q*1024

  // --- frag-read bases
  const char* ard = Wt + (wm * 64 + lrow) * 136 + lk16;   // + mi*2176 + kk*64
  const int   c0  = ((lane >> 4) ^ (lrow & 7)) << 4;      // H read swizzle
  const char* brd = Hb + (wn * 64 + lrow) * 128;          // + ni*2048 + (c0 [^64])

  float4v zero4 = {0.f, 0.f, 0.f, 0.f};
  float4v acc[4][4];
  #pragma unroll
  for (int mi = 0; mi < 4; ++mi)
    #pragma unroll
    for (int ni = 0; ni < 4; ++ni) acc[mi][ni] = zero4;
  float zacc[4] = {0.f, 0.f, 0.f, 0.f};

  // --- prologue: tile 0 (adj regs -> W compute; DMA H; barrier)
  int4v ga[4];
  #pragma unroll
  for (int p = 0; p < 4; ++p)
    ga[p] = __builtin_nontemporal_load((const int4v*)(agp + (size_t)p * 262144));
  #pragma unroll
  for (int q = 0; q < 4; ++q)
    dma16(hdma + q * 65536, hlds + q * 1024);
  {
    const float4v ge0 = *(const float4v*)(efp);
    const float4v ge1 = *(const float4v*)(efp + 4);
    #pragma unroll
    for (int p = 0; p < 4; ++p) {
      float w0 = ga[p][0] ? fmaxf(e1p[p] * ge0[0], f1p[p] * ge0[1]) : 1.0f;
      float w1 = ga[p][1] ? fmaxf(e1p[p] * ge0[2], f1p[p] * ge0[3]) : 1.0f;
      float w2 = ga[p][2] ? fmaxf(e1p[p] * ge1[0], f1p[p] * ge1[1]) : 1.0f;
      float w3 = ga[p][3] ? fmaxf(e1p[p] * ge1[2], f1p[p] * ge1[3]) : 1.0f;
      zacc[p] += (w0 + w1) + (w2 + w3);
      int2v pw;
      asm("v_cvt_pk_bf16_f32 %0, %1, %2" : "=v"(pw[0]) : "v"(w0), "v"(w1));
      asm("v_cvt_pk_bf16_f32 %0, %1, %2" : "=v"(pw[1]) : "v"(w2), "v"(w3));
      *(int2v*)(wwr + p * 4352) = pw;
    }
  }
  __syncthreads();                       // tile 0 ready (drains DMA + LDS)
  #pragma unroll
  for (int p = 0; p < 4; ++p)
    ga[p] = __builtin_nontemporal_load((const int4v*)(agp + (size_t)p * 262144 + 64));

  for (int s = 0; s < 16; ++s) {
    // A: frag reads (bank-balanced) + 32 MFMA/wave on tile s
    #pragma unroll
    for (int kk = 0; kk < 2; ++kk) {
      short8 af[4], bf[4];
      #pragma unroll
      for (int mi = 0; mi < 4; ++mi)
        af[mi] = *(const short8*)(ard + mi * 2176 + kk * 64);
      #pragma unroll
      for (int ni = 0; ni < 4; ++ni)
        bf[ni] = *(const short8*)(brd + ni * 2048 + (c0 ^ (kk << 6)));
      #pragma unroll
      for (int mi = 0; mi < 4; ++mi)
        #pragma unroll
        for (int ni = 0; ni < 4; ++ni)
          acc[mi][ni] = __builtin_amdgcn_mfma_f32_16x16x32_bf16(af[mi], bf[ni], acc[mi][ni], 0, 0, 0);
    }
    __syncthreads();                     // B: all reads of Wt/Hb done

    if (s < 15) {
      // C: DMA H(s+1) into Hb (single buffer — safe after B)
      const int so = (s + 1) * 64;       // shorts
      #pragma unroll
      for (int q = 0; q < 4; ++q)
        dma16(hdma + q * 65536 + so, hlds + q * 1024);

      // D: W-compute (s+1) from prefetched adj regs; covers DMA latency
      const float4v ge0 = *(const float4v*)(efp + (s + 1) * 128);
      const float4v ge1 = *(const float4v*)(efp + (s + 1) * 128 + 4);
      #pragma unroll
      for (int p = 0; p < 4; ++p) {
        float w0 = ga[p][0] ? fmaxf(e1p[p] * ge0[0], f1p[p] * ge0[1]) : 1.0f;
        float w1 = ga[p][1] ? fmaxf(e1p[p] * ge0[2], f1p[p] * ge0[3]) : 1.0f;
        float w2 = ga[p][2] ? fmaxf(e1p[p] * ge1[0], f1p[p] * ge1[1]) : 1.0f;
        float w3 = ga[p][3] ? fmaxf(e1p[p] * ge1[2], f1p[p] * ge1[3]) : 1.0f;
        zacc[p] += (w0 + w1) + (w2 + w3);
        int2v pw;
        asm("v_cvt_pk_bf16_f32 %0, %1, %2" : "=v"(pw[0]) : "v"(w0), "v"(w1));
        asm("v_cvt_pk_bf16_f32 %0, %1, %2" : "=v"(pw[1]) : "v"(w2), "v"(w3));
        *(int2v*)(wwr + p * 4352) = pw;  // E: ds_write W(s+1)
      }

      __syncthreads();                   // G: drains vmcnt(DMA) + lgkm; tiles ready

      // H: issue adj regs for s+2 (covered by next MFMA phase)
      const int sn = (s + 2 < 16) ? (s + 2) * 64 : 15 * 64;
      #pragma unroll
      for (int p = 0; p < 4; ++p)
        ga[p] = __builtin_nontemporal_load((const int4v*)(agp + (size_t)p * 262144 + sn));
    }
  }

  // Z reduce (alias LDS over Wt — all reads finished at barrier B of s=15)
  float* zl = (float*)Wt;
  #pragma unroll
  for (int p = 0; p < 4; ++p) zl[(ar + p * 32) * 16 + aj] = zacc[p];
  __syncthreads();
  if (tid < 128) {
    float z = 0.f;
    #pragma unroll
    for (int g = 0; g < 16; ++g) z += zl[tid * 16 + g];
    Zp[(size_t)blockIdx.y * 8192 + I0 + tid] = z;
  }

  // N partial store (direct, no atomics)
  float* Npb = Np + (size_t)blockIdx.y * 2097152;
  const int r0 = (lane >> 4) << 2;
  #pragma unroll
  for (int mi = 0; mi < 4; ++mi) {
    const int rowb = I0 + wm * 64 + mi * 16 + r0;
    #pragma unroll
    for (int ni = 0; ni < 4; ++ni) {
      const int col = wn * 64 + ni * 16 + lrow;
      #pragma unroll
      for (int r = 0; r < 4; ++r)
        Npb[(size_t)(rowb + r) * 256 + col] = acc[mi][ni][r];
    }
  }
}

// ---------------------------------------------------------------------------
// Kernel 5: out = elu( (sum_y Np) / (sum_y Zp) )   (8 split-K slabs)
// ---------------------------------------------------------------------------
__global__ __launch_bounds__(256) void k_out(
    const float* __restrict__ Np, const float* __restrict__ Zp,
    float* __restrict__ out) {
  const int idx = blockIdx.x * 256 + threadIdx.x;   // float4 index
  const int i = idx >> 6;                           // row (256 feat = 64 f4)
  float z = 0.f;
  #pragma unroll
  for (int y = 0; y < 8; ++y) z += Zp[y * 8192 + i];
  float4v n = {0.f, 0.f, 0.f, 0.f};
  #pragma unroll
  for (int y = 0; y < 8; ++y) {
    float4v v = ((const float4v*)Np)[(size_t)y * 524288 + idx];
    #pragma unroll
    for (int e = 0; e < 4; ++e) n[e] += v[e];
  }
  const float rz = 1.0f / z;
  float4v o;
  #pragma unroll
  for (int e = 0; e < 4; ++e) {
    float v = n[e] * rz;
    o[e] = (v > 0.f) ? v : expm1f(v);
  }
  ((float4v*)out)[idx] = o;
}

// ---------------------------------------------------------------------------
extern "C" void kernel_launch(void* const* d_in, const int* in_sizes, int n_in,
                              void* d_out, int out_size, void* d_ws, size_t ws_size,
                              hipStream_t stream) {
  const int*   adj = (const int*)d_in[0];
  const float* x   = (const float*)d_in[1];
  const float* w   = (const float*)d_in[2];
  const float* a   = (const float*)d_in[3];
  float* out = (float*)d_out;

  // ws layout (~80 MiB of ~1 GiB). hTf (8 MiB f32) lives in d_out
  // transiently; k_out rewrites d_out entirely each call.
  char* ws = (char*)d_ws;
  short*  hT   = (short*)(ws + 0);          //  4 MiB bf16 h^T [256][8192]
  float*  t1p  = (float*)(ws + 4194304);    // 64 KiB
  float*  t2p  = (float*)(ws + 4259840);    // 64 KiB
  float2* e1f1 = (float2*)(ws + 4325376);   // 64 KiB
  float2* ef2  = (float2*)(ws + 4390912);   // 64 KiB
  float*  Zp   = (float*)(ws + 4456448);    // 256 KiB (8 x 8192)
  float*  Np   = (float*)(ws + 16777216);   // 64 MiB (8 x 8192 x 256)
  float*  hTf  = (float*)d_out;             //  8 MiB f32 h^T (transient)

  k_hgemm  <<<128, 256, 0, stream>>>(x, w, hT, hTf);
  k_scores1<<<dim3(32, 2), 256, 0, stream>>>(hTf, a, t1p, t2p);
  k_scores2<<<32, 256, 0, stream>>>(t1p, t2p, e1f1, ef2);
  k_gat    <<<dim3(64, 8), 512, 0, stream>>>(adj, hT, e1f1, ef2, Np, Zp);
  k_out    <<<2048, 256, 0, stream>>>(Np, Zp, out);
}

// Round 12
// 125.954 us; speedup vs baseline: 2.0744x; 1.3177x over previous
//
#include <hip/hip_runtime.h>

typedef short  short8  __attribute__((ext_vector_type(8)));
typedef short  short4v __attribute__((ext_vector_type(4)));
typedef float  float4v __attribute__((ext_vector_type(4)));
typedef int    int4v   __attribute__((ext_vector_type(4)));
typedef int    int2v   __attribute__((ext_vector_type(2)));

#define LOG2E 1.4426950408889634f

static __device__ __forceinline__ short f2bf(float f) {
  unsigned u = __builtin_bit_cast(unsigned, f);
  u = (u + 0x7fffu + ((u >> 16) & 1u)) >> 16;   // RNE
  return (short)u;
}
static __device__ __forceinline__ float bf2f(short s) {
  return __builtin_bit_cast(float, ((unsigned)(unsigned short)s) << 16);
}

typedef __attribute__((address_space(3))) char  as3c;
typedef __attribute__((address_space(1))) char  as1c;
static __device__ __forceinline__ void dma16(const void* g, void* l) {
  __builtin_amdgcn_global_load_lds((const as1c*)g, (as3c*)l, 16, 0, 0);
}

// ---------------------------------------------------------------------------
// Kernel 1: h = x @ w.T  (8192x256, K=256), hi/lo bf16-split MFMA for ~f32
// accuracy. Writes hT bf16 [256][8192] (ws) and hT f32 [256][8192] (d_out,
// transient — consumed by k_scores1; d_out fully rewritten by k_out).
// ---------------------------------------------------------------------------
__global__ __launch_bounds__(256) void k_hgemm(
    const float* __restrict__ x, const float* __restrict__ w,
    short* __restrict__ hT, float* __restrict__ hTf) {
  const int I0   = blockIdx.x * 64;
  const int lane = threadIdx.x & 63;
  const int wn   = threadIdx.x >> 6;       // 4 waves split N (cols)
  const int lrow = lane & 15;
  const int lk8  = (lane >> 4) << 3;

  float4v zero4 = {0.f, 0.f, 0.f, 0.f};
  float4v acc[4][4];
  #pragma unroll
  for (int mi = 0; mi < 4; ++mi)
    #pragma unroll
    for (int ni = 0; ni < 4; ++ni) acc[mi][ni] = zero4;

  for (int k0 = 0; k0 < 256; k0 += 32) {
    short8 ah[4], al[4], bh[4], bl[4];
    #pragma unroll
    for (int mi = 0; mi < 4; ++mi) {
      const float* xp = x + (size_t)(I0 + mi * 16 + lrow) * 256 + k0 + lk8;
      float4v va = *(const float4v*)xp;
      float4v vb = *(const float4v*)(xp + 4);
      #pragma unroll
      for (int e = 0; e < 4; ++e) {
        short h = f2bf(va[e]); ah[mi][e] = h;     al[mi][e]     = f2bf(va[e] - bf2f(h));
        h = f2bf(vb[e]);       ah[mi][4 + e] = h; al[mi][4 + e] = f2bf(vb[e] - bf2f(h));
      }
    }
    #pragma unroll
    for (int ni = 0; ni < 4; ++ni) {
      const float* wp = w + (size_t)(wn * 64 + ni * 16 + lrow) * 256 + k0 + lk8;
      float4v va = *(const float4v*)wp;
      float4v vb = *(const float4v*)(wp + 4);
      #pragma unroll
      for (int e = 0; e < 4; ++e) {
        short h = f2bf(va[e]); bh[ni][e] = h;     bl[ni][e]     = f2bf(va[e] - bf2f(h));
        h = f2bf(vb[e]);       bh[ni][4 + e] = h; bl[ni][4 + e] = f2bf(vb[e] - bf2f(h));
      }
    }
    #pragma unroll
    for (int mi = 0; mi < 4; ++mi)
      #pragma unroll
      for (int ni = 0; ni < 4; ++ni) {
        acc[mi][ni] = __builtin_amdgcn_mfma_f32_16x16x32_bf16(al[mi], bh[ni], acc[mi][ni], 0, 0, 0);
        acc[mi][ni] = __builtin_amdgcn_mfma_f32_16x16x32_bf16(ah[mi], bl[ni], acc[mi][ni], 0, 0, 0);
        acc[mi][ni] = __builtin_amdgcn_mfma_f32_16x16x32_bf16(ah[mi], bh[ni], acc[mi][ni], 0, 0, 0);
      }
  }
  const int r0 = (lane >> 4) << 2;   // C/D: col=lane&15, row=(lane>>4)*4+reg
  #pragma unroll
  for (int mi = 0; mi < 4; ++mi)
    #pragma unroll
    for (int ni = 0; ni < 4; ++ni) {
      const int c   = wn * 64 + ni * 16 + lrow;
      const int row = I0 + mi * 16 + r0;
      float4v v = acc[mi][ni];
      short4v sv;
      #pragma unroll
      for (int r = 0; r < 4; ++r) sv[r] = f2bf(v[r]);
      *(short4v*)(hT + (size_t)c * 8192 + row) = sv;
      *(float4v*)(hTf + (size_t)c * 8192 + row) = v;
    }
}

// ---------------------------------------------------------------------------
// Kernel 2: s1 = h@a1, s2 = h@a2 partials (split-K = 2)
// ---------------------------------------------------------------------------
__global__ __launch_bounds__(256) void k_scores1(
    const float* __restrict__ hTf, const float* __restrict__ a,
    float* __restrict__ t1p, float* __restrict__ t2p) {
  const int i = blockIdx.x * 256 + threadIdx.x;
  const int q = blockIdx.y;
  float s1 = 0.f, s2 = 0.f;
  #pragma unroll 8
  for (int kf = q * 128; kf < q * 128 + 128; ++kf) {
    float hv = hTf[(size_t)kf * 8192 + i];
    s1 = fmaf(hv, a[kf], s1);
    s2 = fmaf(hv, a[256 + kf], s2);
  }
  t1p[q * 8192 + i] = s1;
  t2p[q * 8192 + i] = s2;
}

// ---------------------------------------------------------------------------
// Kernel 3: reduce partials, emit exp2 tables:
//   e1f1[i] = {exp2(t1c), exp2(0.2 t1c)},  ef2[j] = {exp2(t2c), exp2(0.2 t2c)}
// so W = adj ? max(e1*e2, f1*f2) : 1  (exp2 of leaky-relu separable via
// monotonicity — no per-element transcendental in k_gat).
// ---------------------------------------------------------------------------
__global__ __launch_bounds__(256) void k_scores2(
    const float* __restrict__ t1p, const float* __restrict__ t2p,
    float2* __restrict__ e1f1, float2* __restrict__ ef2) {
  const int i = blockIdx.x * 256 + threadIdx.x;
  const float t1 = LOG2E * (t1p[i] + t1p[8192 + i]);
  const float t2 = LOG2E * (t2p[i] + t2p[8192 + i]);
  e1f1[i] = make_float2(exp2f(t1), exp2f(0.2f * t1));
  ef2[i]  = make_float2(exp2f(t2), exp2f(0.2f * t2));
}

// ---------------------------------------------------------------------------
// Kernel 4: fused GAT GEMM — counted-vmcnt pipeline (T3/T4), RACE-FIXED.
// r11's tripwire failure had two protocol bugs: (a) tail underflow — adj
// prefetch stopped at s=29, so at s=30's barrier only the 4 tile-31 DMAs
// were outstanding and vmcnt(4) passed without draining them; (b) issue-
// order fragility — the scheduler may interleave global_load_lds with the
// NT adj loads, breaking the in-order vmcnt arithmetic (m135). Fixes:
// adj issued EVERY s<31 (clamped index -> always exactly 4 adj behind the
// 4 DMAs) and sched_barrier(0) pinning each issue group in program order.
// Schedule per tile: DMA H(s+1) | ds_read kk0 + 16 MFMA | W-compute(s+1)
// (VALU covers DMA) | issue adj(s+2) | ds_read kk1 + 16 MFMA |
// s_waitcnt vmcnt(4) lgkmcnt(0) + raw s_barrier (adj loads stay in
// flight ACROSS the barrier — never drain to 0 in the loop).
// BM=128 BN=256 BK=64, split-K=4: grid (64,4)=256 blocks = 1/CU, 114KB
// LDS (Wt[2] 136B-pad rows + Ht[2] linear/DMA src-swizzled + ef table).
// ---------------------------------------------------------------------------
__global__ __launch_bounds__(512) void k_gat(
    const int* __restrict__ adj, const short* __restrict__ hT,
    const float2* __restrict__ e1f1, const float2* __restrict__ ef2,
    float* __restrict__ Np, float* __restrict__ Zp) {
  __shared__ __align__(16) char Wt[2][17408];   // 128 rows x 136B (64j bf16 + 8B pad)
  __shared__ __align__(16) char Hb[2][32768];   // 256 rows x 128B, linear, src-swz
  __shared__ __align__(16) char Elds[16384];    // ef2 slab: 2048 x {e,f} f32

  const int tid = threadIdx.x, lane = tid & 63, wave = tid >> 6;
  const int wm = wave >> 2, wn = wave & 3;
  const int lrow = lane & 15, lk16 = (lane >> 4) << 4;
  const int I0 = blockIdx.x * 128;
  const int j0 = blockIdx.y * 2048;

  // --- W staging map: thread -> rows ar+32p (p=0..3), 4-j chunk aj
  const int ar = tid >> 4, aj = tid & 15;
  const int* agp = adj + (size_t)(I0 + ar) * 8192 + j0 + aj * 4;
  float e1p[4], f1p[4];
  #pragma unroll
  for (int p = 0; p < 4; ++p) {
    float2 v = e1f1[I0 + p * 32 + ar];
    e1p[p] = v.x; f1p[p] = v.y;
  }
  const int wwo = ar * 136 + aj * 8;            // + p*4352, + buf

  // --- H DMA: wave -> rows wave*32..+31; lane l -> row +(l>>3),
  //     global chunk (l&7)^(l>>3) (pre-swizzle; LDS stays linear)
  const int l8 = lane >> 3, l7 = lane & 7;
  const short* hdma = hT + (size_t)(wave * 32 + l8) * 8192 + j0 + (l7 ^ l8) * 8;
  const int hlo = wave * 4096;                  // + q*1024, + buf

  // --- frag-read bases
  const int ardo = (wm * 64 + lrow) * 136 + lk16;      // + mi*2176 + kk*64
  const int brdo = (wn * 64 + lrow) * 128;             // + ni*2048 + (c0 ^ kk<<6)
  const int c0   = ((lane >> 4) ^ (lrow & 7)) << 4;

  float4v zero4 = {0.f, 0.f, 0.f, 0.f};
  float4v acc[4][4];
  #pragma unroll
  for (int mi = 0; mi < 4; ++mi)
    #pragma unroll
    for (int ni = 0; ni < 4; ++ni) acc[mi][ni] = zero4;
  float zacc[4] = {0.f, 0.f, 0.f, 0.f};
  int4v ga[4];

  // W-compute for tile T from ga + Elds, writes to DST (Wt buffer base)
#define WCOMP(T, DST)                                                         \
  { const float4v ge0 = *(const float4v*)(Elds + (T) * 512 + aj * 32);        \
    const float4v ge1 = *(const float4v*)(Elds + (T) * 512 + aj * 32 + 16);   \
    _Pragma("unroll")                                                         \
    for (int p = 0; p < 4; ++p) {                                             \
      float w0 = ga[p][0] ? fmaxf(e1p[p] * ge0[0], f1p[p] * ge0[1]) : 1.0f;   \
      float w1 = ga[p][1] ? fmaxf(e1p[p] * ge0[2], f1p[p] * ge0[3]) : 1.0f;   \
      float w2 = ga[p][2] ? fmaxf(e1p[p] * ge1[0], f1p[p] * ge1[1]) : 1.0f;   \
      float w3 = ga[p][3] ? fmaxf(e1p[p] * ge1[2], f1p[p] * ge1[3]) : 1.0f;   \
      zacc[p] += (w0 + w1) + (w2 + w3);                                       \
      int2v pw;                                                               \
      asm("v_cvt_pk_bf16_f32 %0, %1, %2" : "=v"(pw[0]) : "v"(w0), "v"(w1));   \
      asm("v_cvt_pk_bf16_f32 %0, %1, %2" : "=v"(pw[1]) : "v"(w2), "v"(w3));   \
      *(int2v*)((DST) + wwo + p * 4352) = pw;                                 \
    } }

  // --- prologue: ef table -> LDS; tile-0 staging; counted-wait barrier
  {
    const char* esrc = (const char*)(ef2 + j0);
    *(float4v*)(Elds + tid * 32)      = *(const float4v*)(esrc + tid * 32);
    *(float4v*)(Elds + tid * 32 + 16) = *(const float4v*)(esrc + tid * 32 + 16);
  }
  __syncthreads();                              // Elds visible
  #pragma unroll
  for (int p = 0; p < 4; ++p)
    ga[p] = __builtin_nontemporal_load((const int4v*)(agp + (size_t)p * 262144));
  __builtin_amdgcn_sched_barrier(0);            // pin: adj0 issued first
  #pragma unroll
  for (int q = 0; q < 4; ++q)
    dma16(hdma + q * 65536, Hb[0] + hlo + q * 1024);
  __builtin_amdgcn_sched_barrier(0);            // pin: DMAs before adj1
  WCOMP(0, Wt[0]);
  #pragma unroll
  for (int p = 0; p < 4; ++p)
    ga[p] = __builtin_nontemporal_load((const int4v*)(agp + (size_t)p * 262144 + 64));
  __builtin_amdgcn_sched_barrier(0);            // pin: adj1 after DMAs
  asm volatile("s_waitcnt vmcnt(4) lgkmcnt(0)" ::: "memory");
  __builtin_amdgcn_s_barrier();
  __builtin_amdgcn_sched_barrier(0);

  #pragma unroll 2
  for (int s = 0; s < 32; ++s) {
    const int cur = s & 1, nx = cur ^ 1;
    // P1: DMA H(s+1) into Hb[nx]
    if (s < 31) {
      const int so = (s + 1) * 64;              // shorts
      #pragma unroll
      for (int q = 0; q < 4; ++q)
        dma16(hdma + so + q * 65536, Hb[nx] + hlo + q * 1024);
    }
    __builtin_amdgcn_sched_barrier(0);          // pin: DMA group issued here
    // P2: kk=0 frags + 16 MFMA
    short8 af[4], bf[4];
    #pragma unroll
    for (int mi = 0; mi < 4; ++mi) af[mi] = *(const short8*)(Wt[cur] + ardo + mi * 2176);
    #pragma unroll
    for (int ni = 0; ni < 4; ++ni) bf[ni] = *(const short8*)(Hb[cur] + brdo + ni * 2048 + c0);
    #pragma unroll
    for (int mi = 0; mi < 4; ++mi)
      #pragma unroll
      for (int ni = 0; ni < 4; ++ni)
        acc[mi][ni] = __builtin_amdgcn_mfma_f32_16x16x32_bf16(af[mi], bf[ni], acc[mi][ni], 0, 0, 0);
    // P3: W-compute(s+1) -> Wt[nx] (VALU covers the DMA in flight)
    if (s < 31) WCOMP(s + 1, Wt[nx]);
    // P4: issue adj — EVERY s<31 (clamped) so each barrier has exactly 4
    //     adj ops in flight behind the 4 DMAs (vmcnt(4) drains DMAs only)
    if (s < 31) {
      const int sp = (s + 2 < 32) ? s + 2 : 31;
      const int so = sp * 64;                   // ints
      #pragma unroll
      for (int p = 0; p < 4; ++p)
        ga[p] = __builtin_nontemporal_load((const int4v*)(agp + (size_t)p * 262144 + so));
    }
    __builtin_amdgcn_sched_barrier(0);          // pin: adj group after DMAs
    // P5: kk=1 frags + 16 MFMA
    #pragma unroll
    for (int mi = 0; mi < 4; ++mi) af[mi] = *(const short8*)(Wt[cur] + ardo + mi * 2176 + 64);
    #pragma unroll
    for (int ni = 0; ni < 4; ++ni) bf[ni] = *(const short8*)(Hb[cur] + brdo + ni * 2048 + (c0 ^ 64));
    #pragma unroll
    for (int mi = 0; mi < 4; ++mi)
      #pragma unroll
      for (int ni = 0; ni < 4; ++ni)
        acc[mi][ni] = __builtin_amdgcn_mfma_f32_16x16x32_bf16(af[mi], bf[ni], acc[mi][ni], 0, 0, 0);
    // P6: counted drain (DMAs only; adj loads stay in flight) + raw barrier
    if (s < 31) {
      asm volatile("s_waitcnt vmcnt(4) lgkmcnt(0)" ::: "memory");
      __builtin_amdgcn_s_barrier();
      __builtin_amdgcn_sched_barrier(0);
    }
  }
#undef WCOMP

  // Z reduce: per-thread partials -> LDS (alias over Elds) -> 1/row
  __syncthreads();
  float* zl = (float*)Elds;
  #pragma unroll
  for (int p = 0; p < 4; ++p) zl[(ar + p * 32) * 16 + aj] = zacc[p];
  __syncthreads();
  if (tid < 128) {
    float z = 0.f;
    #pragma unroll
    for (int g = 0; g < 16; ++g) z += zl[tid * 16 + g];
    Zp[(size_t)blockIdx.y * 8192 + I0 + tid] = z;
  }

  // N partial store (direct, no atomics)
  float* Npb = Np + (size_t)blockIdx.y * 2097152;
  const int r0 = (lane >> 4) << 2;
  #pragma unroll
  for (int mi = 0; mi < 4; ++mi) {
    const int rowb = I0 + wm * 64 + mi * 16 + r0;
    #pragma unroll
    for (int ni = 0; ni < 4; ++ni) {
      const int col = wn * 64 + ni * 16 + lrow;
      #pragma unroll
      for (int r = 0; r < 4; ++r)
        Npb[(size_t)(rowb + r) * 256 + col] = acc[mi][ni][r];
    }
  }
}

// ---------------------------------------------------------------------------
// Kernel 5: out = elu( (sum_y Np) / (sum_y Zp) )   (4 split-K slabs)
// ---------------------------------------------------------------------------
__global__ __launch_bounds__(256) void k_out(
    const float* __restrict__ Np, const float* __restrict__ Zp,
    float* __restrict__ out) {
  const int idx = blockIdx.x * 256 + threadIdx.x;   // float4 index
  const int i = idx >> 6;                           // row (256 feat = 64 f4)
  float z = 0.f;
  #pragma unroll
  for (int y = 0; y < 4; ++y) z += Zp[y * 8192 + i];
  float4v n = {0.f, 0.f, 0.f, 0.f};
  #pragma unroll
  for (int y = 0; y < 4; ++y) {
    float4v v = ((const float4v*)Np)[(size_t)y * 524288 + idx];
    #pragma unroll
    for (int e = 0; e < 4; ++e) n[e] += v[e];
  }
  const float rz = 1.0f / z;
  float4v o;
  #pragma unroll
  for (int e = 0; e < 4; ++e) {
    float v = n[e] * rz;
    o[e] = (v > 0.f) ? v : expm1f(v);
  }
  ((float4v*)out)[idx] = o;
}

// ---------------------------------------------------------------------------
extern "C" void kernel_launch(void* const* d_in, const int* in_sizes, int n_in,
                              void* d_out, int out_size, void* d_ws, size_t ws_size,
                              hipStream_t stream) {
  const int*   adj = (const int*)d_in[0];
  const float* x   = (const float*)d_in[1];
  const float* w   = (const float*)d_in[2];
  const float* a   = (const float*)d_in[3];
  float* out = (float*)d_out;

  // ws layout (~48 MiB of ~1 GiB). hTf (8 MiB f32) lives in d_out
  // transiently; k_out rewrites d_out entirely each call.
  char* ws = (char*)d_ws;
  short*  hT   = (short*)(ws + 0);          //  4 MiB bf16 h^T [256][8192]
  float*  t1p  = (float*)(ws + 4194304);    // 64 KiB
  float*  t2p  = (float*)(ws + 4259840);    // 64 KiB
  float2* e1f1 = (float2*)(ws + 4325376);   // 64 KiB
  float2* ef2  = (float2*)(ws + 4390912);   // 64 KiB
  float*  Zp   = (float*)(ws + 4456448);    // 128 KiB (4 x 8192)
  float*  Np   = (float*)(ws + 16777216);   // 32 MiB (4 x 8192 x 256)
  float*  hTf  = (float*)d_out;             //  8 MiB f32 h^T (transient)

  k_hgemm  <<<128, 256, 0, stream>>>(x, w, hT, hTf);
  k_scores1<<<dim3(32, 2), 256, 0, stream>>>(hTf, a, t1p, t2p);
  k_scores2<<<32, 256, 0, stream>>>(t1p, t2p, e1f1, ef2);
  k_gat    <<<dim3(64, 4), 512, 0, stream>>>(adj, hT, e1f1, ef2, Np, Zp);
  k_out    <<<2048, 256, 0, stream>>>(Np, Zp, out);
}